// Round 1
// baseline (1918.121 us; speedup 1.0000x reference)
//
#include <hip/hip_runtime.h>

// Problem constants: x (P,B,C,H,W)=(8,4,32,256,256) fp32; w* (C,C,P,M1,M2)=(32,32,8,32,32)
// Kept modes: ky in [0,32) u [224,256)  (s=0..63, ky = s<32 ? s : s+192), kx in [0,32)

constexpr float TWO_PI = 6.28318530717958647692f;

// ---------------- Kernel 1: forward truncated DFT per plane ----------------
// One workgroup per (p,b,c) plane (1024 blocks, 256 threads).
// Stage A: X1[h][kx] = sum_w x[h][w] e^{-2pi i w kx/256}   (kx split in halves of 16)
// Stage B: X2[s][kx] = sum_h X1[h][kx] e^{-2pi i h ky(s)/256}
__global__ __launch_bounds__(256) void fwd_dft(const float* __restrict__ x,
                                               float2* __restrict__ X2) {
  __shared__ float2 tw[256];                    // 2 KB   e^{+i 2pi t/256} = (cos, sin)
  __shared__ alignas(16) float rowbuf[16][256]; // 16 KB
  __shared__ alignas(16) float2 X1[256][16];    // 32 KB
  const int t = threadIdx.x;
  {
    float ang = (float)t * (TWO_PI / 256.0f);
    tw[t] = make_float2(cosf(ang), sinf(ang));
  }
  const float* xp = x + (size_t)blockIdx.x * (256 * 256);
  const int kx2 = t & 15;
  const int g = t >> 4;          // 0..15
  __syncthreads();

  for (int khalf = 0; khalf < 2; ++khalf) {
    const int kx = khalf * 16 + kx2;
    // ---- Stage A over 16 chunks of 16 rows ----
    for (int hb = 0; hb < 16; ++hb) {
      const float4* src = (const float4*)(xp + hb * 16 * 256);
      float4* dst = (float4*)&rowbuf[0][0];
#pragma unroll
      for (int q = 0; q < 4; ++q) dst[t + 256 * q] = src[t + 256 * q];
      __syncthreads();
      float re = 0.f, im = 0.f;
#pragma unroll 8
      for (int w = 0; w < 256; ++w) {
        float v = rowbuf[g][w];
        float2 z = tw[(w * kx) & 255];
        re = fmaf(v, z.x, re);    // v * cos
        im = fmaf(v, -z.y, im);   // -v * sin
      }
      X1[hb * 16 + g][kx2] = make_float2(re, im);
      __syncthreads();
    }
    // ---- Stage B: each thread does 4 s values for its kx ----
#pragma unroll
    for (int j = 0; j < 4; ++j) {
      const int s = g * 4 + j;
      const int ky = (s < 32) ? s : (s + 192);
      float re = 0.f, im = 0.f;
#pragma unroll 8
      for (int h = 0; h < 256; ++h) {
        float2 v = X1[h][kx2];
        float2 z = tw[(h * ky) & 255];
        // v * (cos - i sin)
        re += v.x * z.x + v.y * z.y;
        im += v.y * z.x - v.x * z.y;
      }
      X2[(size_t)blockIdx.x * 2048 + s * 32 + kx] = make_float2(re, im);
    }
    __syncthreads();  // before reusing rowbuf/X1 for second kx half
  }
}

// ---------------- Kernel 2: channel mixing ----------------
// out[p,b,o,s,kx] = sum_i in[p,b,i,s,kx] * w[i,o,p,y(s),kx]   (complex)
// thread per (p,o,s,kx): 524288 threads = 2048 blocks. Weights read exactly once, coalesced.
__global__ __launch_bounds__(256) void mix(const float2* __restrict__ X2,
                                           const float* __restrict__ w1re,
                                           const float* __restrict__ w1im,
                                           const float* __restrict__ w4re,
                                           const float* __restrict__ w4im,
                                           float2* __restrict__ Y2) {
  const int n = blockIdx.x * 256 + threadIdx.x;
  const int kx = n & 31;
  const int s = (n >> 5) & 63;
  const int o = (n >> 11) & 31;
  const int p = n >> 16;
  const float* wre;
  const float* wim;
  int y;
  if (s < 32) { wre = w1re; wim = w1im; y = s; }
  else        { wre = w4re; wim = w4im; y = s - 32; }
  // w layout (i,o,p,y,x): strides i:262144, o:8192, p:1024, y:32, x:1
  const size_t wbase = (size_t)o * 8192 + (size_t)p * 1024 + y * 32 + kx;
  // X2/Y2 layout: plane=(p*4+b)*32+c, then [s][kx] float2
  const size_t in_base = ((size_t)p * 4 * 32) * 2048 + s * 32 + kx;  // b stride 65536, i stride 2048
  float2 acc[4] = {make_float2(0.f, 0.f), make_float2(0.f, 0.f),
                   make_float2(0.f, 0.f), make_float2(0.f, 0.f)};
#pragma unroll 4
  for (int i = 0; i < 32; ++i) {
    const float wr = wre[wbase + (size_t)i * 262144];
    const float wi = wim[wbase + (size_t)i * 262144];
#pragma unroll
    for (int b = 0; b < 4; ++b) {
      float2 v = X2[in_base + (size_t)b * 65536 + (size_t)i * 2048];
      acc[b].x += v.x * wr - v.y * wi;
      acc[b].y += v.x * wi + v.y * wr;
    }
  }
  const size_t out_base = ((size_t)p * 4 * 32 + o) * 2048 + s * 32 + kx;
#pragma unroll
  for (int b = 0; b < 4; ++b) Y2[out_base + (size_t)b * 65536] = acc[b];
}

// ---------------- Kernel 3: inverse truncated DFT per plane ----------------
// Stage D: Y1[h][kx] = (1/(H*W)) * scale(kx) * sum_s Y2[s][kx] e^{+2pi i h ky(s)/256}
// Stage E: out[h][w]  = sum_kx Re(Y1[h][kx] e^{+2pi i w kx/256})   (2x folded into scale)
__global__ __launch_bounds__(256) void inv_dft(const float2* __restrict__ Y2,
                                               float* __restrict__ out) {
  __shared__ float2 tw[256];                  // 2 KB
  __shared__ alignas(16) float2 Yin[64][32];  // 16 KB
  __shared__ alignas(16) float2 Y1[128][32];  // 32 KB
  const int t = threadIdx.x;
  {
    float ang = (float)t * (TWO_PI / 256.0f);
    tw[t] = make_float2(cosf(ang), sinf(ang));
  }
  {
    const float4* src = (const float4*)(Y2 + (size_t)blockIdx.x * 2048);
    float4* dst = (float4*)&Yin[0][0];
#pragma unroll
    for (int q = 0; q < 4; ++q) dst[t + 256 * q] = src[t + 256 * q];
  }
  __syncthreads();
  const int kx = t & 31;
  const int g = t >> 5;  // 0..7
  float* op = out + (size_t)blockIdx.x * 65536;
  const float scale = (kx == 0) ? (1.f / 65536.f) : (2.f / 65536.f);

  for (int half = 0; half < 2; ++half) {
    // ---- Stage D: 128 h rows per half ----
#pragma unroll
    for (int j = 0; j < 16; ++j) {
      const int hh = g * 16 + j;        // 0..127
      const int h = half * 128 + hh;
      float re = 0.f, im = 0.f;
#pragma unroll 8
      for (int s = 0; s < 32; ++s) {    // ky = s
        float2 v = Yin[s][kx];
        float2 z = tw[(h * s) & 255];
        re += v.x * z.x - v.y * z.y;    // v * (cos + i sin)
        im += v.x * z.y + v.y * z.x;
      }
#pragma unroll 8
      for (int s = 32; s < 64; ++s) {   // ky = s + 192
        float2 v = Yin[s][kx];
        float2 z = tw[(h * (s + 192)) & 255];
        re += v.x * z.x - v.y * z.y;
        im += v.x * z.y + v.y * z.x;
      }
      Y1[hh][kx] = make_float2(re * scale, im * scale);
    }
    __syncthreads();
    // ---- Stage E: thread t = output column w ----
    for (int hh = 0; hh < 128; ++hh) {
      const int h = half * 128 + hh;
      float acc = 0.f;
#pragma unroll 8
      for (int k2 = 0; k2 < 32; ++k2) {
        float2 v = Y1[hh][k2];          // broadcast across all lanes
        float2 z = tw[(t * k2) & 255];
        acc += v.x * z.x - v.y * z.y;   // Re(v * e^{+i th})
      }
      op[h * 256 + t] = acc;
    }
    __syncthreads();  // before overwriting Y1 next half
  }
}

extern "C" void kernel_launch(void* const* d_in, const int* in_sizes, int n_in,
                              void* d_out, int out_size, void* d_ws, size_t ws_size,
                              hipStream_t stream) {
  const float* x = (const float*)d_in[0];
  const float* w1re = (const float*)d_in[1];
  const float* w1im = (const float*)d_in[2];
  const float* w4re = (const float*)d_in[3];
  const float* w4im = (const float*)d_in[4];
  float* out = (float*)d_out;
  float2* X2 = (float2*)d_ws;                 // 1024 planes * 2048 modes * 8 B = 16 MB
  float2* Y2 = X2 + (size_t)1024 * 2048;      // another 16 MB

  fwd_dft<<<1024, 256, 0, stream>>>(x, X2);
  mix<<<2048, 256, 0, stream>>>(X2, w1re, w1im, w4re, w4im, Y2);
  inv_dft<<<1024, 256, 0, stream>>>(Y2, out);
}

// Round 2
// 930.896 us; speedup vs baseline: 2.0605x; 2.0605x over previous
//
#include <hip/hip_runtime.h>

// x (P,B,C,H,W)=(8,4,32,256,256) fp32; w* (C,C,P,M1,M2)=(32,32,8,32,32)
// Kept modes: ky in [0,32) u [224,256)  (s=0..63, ky = s<32 ? s : s+192), kx in [0,32)

constexpr float TWO_PI = 6.28318530717958647692f;

// ---------------- Kernel 1: forward truncated DFT per plane ----------------
// Stage A: X1[h][kx] = sum_{w0<128} u_{kx&1}[h][w0] e^{-2pi i w0 kx/256}
//   where u_0 = x[w0]+x[w0+128], u_1 = x[w0]-x[w0+128]   (h-parity fold of w)
//   Twiddles in registers via w0 = 16*w1 + w00: A[w00]*Bt[w1].
// Fold: X1[h0] +/- X1[h0+128] in place (parity of ky(s) = parity of s).
// Stage B: X2[s][kx] = sum_{h0<128} X1fold[s&1][h0][kx] e^{-2pi i h0 ky(s)/256}
__global__ __launch_bounds__(256) void fwd_dft(const float* __restrict__ x,
                                               float2* __restrict__ X2) {
  __shared__ float2 tw[256];          // e^{+2pi i t/256}
  __shared__ float u[16][260];        // [row][w0*2 + parity], padded (260%32=4)
  __shared__ float2 X1[256][16];      // [h][kxh]
  const int t = threadIdx.x;
  {
    float a = (float)t * (TWO_PI / 256.f);
    tw[t] = make_float2(cosf(a), sinf(a));
  }
  const float* xp = x + (size_t)blockIdx.x * 65536;
  const int lane = t & 63, wv = t >> 6;
  const int kxh = lane & 15;   // 0..15
  const int g = lane >> 4;     // 0..3
  const int par = kxh & 1;

  for (int half = 0; half < 2; ++half) {
    const int kx = half * 16 + kxh;
    // register twiddles: A[w00] = e^{-2pi i w00 kx/256}, Bt[w1] = e^{-2pi i w1 kxh/16}
    float2 A[16], Bt[8];
#pragma unroll
    for (int w00 = 0; w00 < 16; ++w00) {
      float a = (TWO_PI / 256.f) * (float)(w00 * kx);
      A[w00] = make_float2(cosf(a), -sinf(a));
    }
#pragma unroll
    for (int w1 = 0; w1 < 8; ++w1) {
      float a = (TWO_PI / 16.f) * (float)(w1 * kxh);
      Bt[w1] = make_float2(cosf(a), -sinf(a));
    }
    // ---- Stage A over 16 chunks of 16 h rows ----
    for (int chunk = 0; chunk < 16; ++chunk) {
      __syncthreads();  // protect u from previous chunk's readers
#pragma unroll
      for (int r = 0; r < 2; ++r) {
        int task = t + 256 * r;           // 512 tasks: (row, w4)
        int row = task >> 5;              // 0..15
        int w4 = task & 31;               // float4 group, w0 = 4*w4..
        const float4 a4 = *(const float4*)(xp + (chunk * 16 + row) * 256 + w4 * 4);
        const float4 b4 = *(const float4*)(xp + (chunk * 16 + row) * 256 + w4 * 4 + 128);
        *(float4*)&u[row][w4 * 8] =
            make_float4(a4.x + b4.x, a4.x - b4.x, a4.y + b4.y, a4.y - b4.y);
        *(float4*)&u[row][w4 * 8 + 4] =
            make_float4(a4.z + b4.z, a4.z - b4.z, a4.w + b4.w, a4.w - b4.w);
      }
      __syncthreads();
      const int hrow = wv * 4 + g;
      const float* up = &u[hrow][par];
      float accx = 0.f, accy = 0.f;
#pragma unroll
      for (int w00 = 0; w00 < 16; ++w00) {
        float Sx = 0.f, Sy = 0.f;
#pragma unroll
        for (int w1 = 0; w1 < 8; ++w1) {
          float uv = up[(w1 * 16 + w00) * 2];
          Sx = fmaf(uv, Bt[w1].x, Sx);
          Sy = fmaf(uv, Bt[w1].y, Sy);
        }
        accx += A[w00].x * Sx - A[w00].y * Sy;
        accy += A[w00].x * Sy + A[w00].y * Sx;
      }
      X1[chunk * 16 + hrow][kxh] = make_float2(accx, accy);
    }
    __syncthreads();
    // ---- fold h parity in place: rows [0,128)=sum, [128,256)=diff ----
#pragma unroll
    for (int r = 0; r < 8; ++r) {
      int idx = t + 256 * r;              // 2048 tasks: (h0, k)
      int h0 = idx >> 4, k = idx & 15;
      float2 a = X1[h0][k], b = X1[h0 + 128][k];
      X1[h0][k] = make_float2(a.x + b.x, a.y + b.y);
      X1[h0 + 128][k] = make_float2(a.x - b.x, a.y - b.y);
    }
    __syncthreads();
    // ---- Stage B ----
    float2* X2p = X2 + (size_t)blockIdx.x * 2048;
    for (int iter = 0; iter < 4; ++iter) {
      int s = wv * 16 + iter * 4 + g;
      int ky = (s < 32) ? s : s + 192;
      const float2* Xrow = &X1[(s & 1) * 128][0];
      float ax = 0.f, ay = 0.f;
#pragma unroll 8
      for (int h0 = 0; h0 < 128; ++h0) {
        float2 v = Xrow[h0 * 16 + kxh];
        float2 z = tw[(h0 * ky) & 255];
        // v * (cos - i sin)
        ax += v.x * z.x + v.y * z.y;
        ay += v.y * z.x - v.x * z.y;
      }
      X2p[s * 32 + kx] = make_float2(ax, ay);
    }
    __syncthreads();  // before next half reuses u/X1
  }
}

// ---------------- Kernel 2: channel mixing (unchanged) ----------------
__global__ __launch_bounds__(256) void mix(const float2* __restrict__ X2,
                                           const float* __restrict__ w1re,
                                           const float* __restrict__ w1im,
                                           const float* __restrict__ w4re,
                                           const float* __restrict__ w4im,
                                           float2* __restrict__ Y2) {
  const int n = blockIdx.x * 256 + threadIdx.x;
  const int kx = n & 31;
  const int s = (n >> 5) & 63;
  const int o = (n >> 11) & 31;
  const int p = n >> 16;
  const float* wre;
  const float* wim;
  int y;
  if (s < 32) { wre = w1re; wim = w1im; y = s; }
  else        { wre = w4re; wim = w4im; y = s - 32; }
  const size_t wbase = (size_t)o * 8192 + (size_t)p * 1024 + y * 32 + kx;
  const size_t in_base = ((size_t)p * 4 * 32) * 2048 + s * 32 + kx;
  float2 acc[4] = {make_float2(0.f, 0.f), make_float2(0.f, 0.f),
                   make_float2(0.f, 0.f), make_float2(0.f, 0.f)};
#pragma unroll 4
  for (int i = 0; i < 32; ++i) {
    const float wr = wre[wbase + (size_t)i * 262144];
    const float wi = wim[wbase + (size_t)i * 262144];
#pragma unroll
    for (int b = 0; b < 4; ++b) {
      float2 v = X2[in_base + (size_t)b * 65536 + (size_t)i * 2048];
      acc[b].x += v.x * wr - v.y * wi;
      acc[b].y += v.x * wi + v.y * wr;
    }
  }
  const size_t out_base = ((size_t)p * 4 * 32 + o) * 2048 + s * 32 + kx;
#pragma unroll
  for (int b = 0; b < 4; ++b) Y2[out_base + (size_t)b * 65536] = acc[b];
}

// ---------------- Kernel 3: inverse truncated DFT per plane ----------------
// Stage D (per h0<64, quad q): Y1[h0+64q][kx] = scale * sum_r i^{qr} B_r,
//   B_r = sum_{s≡r mod 4} Y2[s][kx] e^{+2pi i h0 ky(s)/256}   (i^{ky}=i^{s})
// Stage E (per h row, lane w0<64): out[h][w0+64q'] from partials P_r over k mod 4,
//   z_k = Y1[h][k] * T[k] with T in registers; Re(i^{q'k} z_k) recombined.
__global__ __launch_bounds__(256) void inv_dft(const float2* __restrict__ Y2,
                                               float* __restrict__ out) {
  __shared__ float2 tw[256];
  __shared__ float2 Ys[64 * 32];       // input modes [s][kx]
  __shared__ float2 Y1c[4 * 32 * 32];  // [q][hh][k] compact quad rows
  const int t = threadIdx.x;
  {
    float a = (float)t * (TWO_PI / 256.f);
    tw[t] = make_float2(cosf(a), sinf(a));
  }
  {
    const float4* src = (const float4*)(Y2 + (size_t)blockIdx.x * 2048);
    float4* dst = (float4*)Ys;
#pragma unroll
    for (int q = 0; q < 4; ++q) dst[t + 256 * q] = src[t + 256 * q];
  }
  const int lane = t & 63, wv = t >> 6;
  const int kx = lane & 31, hg = lane >> 5;
  const float scale = (kx == 0) ? (1.f / 65536.f) : (2.f / 65536.f);
  // Stage E register twiddles: T[k] = e^{+2pi i lane*k/256}
  float2 T[32];
#pragma unroll
  for (int k = 0; k < 32; ++k) {
    float a = (TWO_PI / 256.f) * (float)(lane * k);
    T[k] = make_float2(cosf(a), sinf(a));
  }
  __syncthreads();
  float* op = out + (size_t)blockIdx.x * 65536;

  for (int pass = 0; pass < 2; ++pass) {
    const int h0base = pass * 32;
    // ---- Stage D ----
    for (int iter = 0; iter < 4; ++iter) {
      const int h0 = h0base + wv * 8 + iter * 2 + hg;
      float B0x = 0, B0y = 0, B1x = 0, B1y = 0;
      float B2x = 0, B2y = 0, B3x = 0, B3y = 0;
#define DSTEP(S, KY, BX, BY)                              \
  {                                                       \
    float2 v = Ys[(S) * 32 + kx];                         \
    float2 z = tw[(h0 * (KY)) & 255];                     \
    BX += v.x * z.x - v.y * z.y;                          \
    BY += v.x * z.y + v.y * z.x;                          \
  }
#pragma unroll 4
      for (int sb = 0; sb < 32; sb += 4) {
        DSTEP(sb + 0, sb + 0, B0x, B0y);
        DSTEP(sb + 1, sb + 1, B1x, B1y);
        DSTEP(sb + 2, sb + 2, B2x, B2y);
        DSTEP(sb + 3, sb + 3, B3x, B3y);
      }
#pragma unroll 4
      for (int sb = 32; sb < 64; sb += 4) {
        DSTEP(sb + 0, sb + 192, B0x, B0y);
        DSTEP(sb + 1, sb + 193, B1x, B1y);
        DSTEP(sb + 2, sb + 194, B2x, B2y);
        DSTEP(sb + 3, sb + 195, B3x, B3y);
      }
#undef DSTEP
      const float Ex = B0x + B2x, Ey = B0y + B2y, Fx = B1x + B3x, Fy = B1y + B3y;
      const float Gx = B0x - B2x, Gy = B0y - B2y, Hx = B1x - B3x, Hy = B1y - B3y;
      float2* yb = &Y1c[(h0 - h0base) * 32 + kx];
      yb[0]    = make_float2((Ex + Fx) * scale, (Ey + Fy) * scale);
      yb[1024] = make_float2((Gx - Hy) * scale, (Gy + Hx) * scale);
      yb[2048] = make_float2((Ex - Fx) * scale, (Ey - Fy) * scale);
      yb[3072] = make_float2((Gx + Hy) * scale, (Gy - Hx) * scale);
    }
    __syncthreads();
    // ---- Stage E: wave wv owns quadrant q=wv ----
    for (int j = 0; j < 32; ++j) {
      const float2* row = &Y1c[wv * 1024 + j * 32];
      float p0 = 0, p2 = 0, P1x = 0, P1y = 0, P3x = 0, P3y = 0;
#pragma unroll
      for (int kb = 0; kb < 32; kb += 4) {
        float4 v01 = *(const float4*)(row + kb);
        float4 v23 = *(const float4*)(row + kb + 2);
        p0  += v01.x * T[kb].x     - v01.y * T[kb].y;
        P1x += v01.z * T[kb + 1].x - v01.w * T[kb + 1].y;
        P1y += v01.z * T[kb + 1].y + v01.w * T[kb + 1].x;
        p2  += v23.x * T[kb + 2].x - v23.y * T[kb + 2].y;
        P3x += v23.z * T[kb + 3].x - v23.w * T[kb + 3].y;
        P3y += v23.z * T[kb + 3].y + v23.w * T[kb + 3].x;
      }
      const int h = wv * 64 + h0base + j;
      float* o = op + h * 256 + lane;
      o[0]   = p0 + P1x + p2 + P3x;
      o[64]  = p0 - P1y - p2 + P3y;
      o[128] = p0 - P1x + p2 - P3x;
      o[192] = p0 + P1y - p2 - P3y;
    }
    __syncthreads();  // before next pass overwrites Y1c
  }
}

extern "C" void kernel_launch(void* const* d_in, const int* in_sizes, int n_in,
                              void* d_out, int out_size, void* d_ws, size_t ws_size,
                              hipStream_t stream) {
  const float* x = (const float*)d_in[0];
  const float* w1re = (const float*)d_in[1];
  const float* w1im = (const float*)d_in[2];
  const float* w4re = (const float*)d_in[3];
  const float* w4im = (const float*)d_in[4];
  float* out = (float*)d_out;
  float2* X2 = (float2*)d_ws;                 // 16 MB
  float2* Y2 = X2 + (size_t)1024 * 2048;      // 16 MB

  fwd_dft<<<1024, 256, 0, stream>>>(x, X2);
  mix<<<2048, 256, 0, stream>>>(X2, w1re, w1im, w4re, w4im, Y2);
  inv_dft<<<1024, 256, 0, stream>>>(Y2, out);
}